// Round 9
// baseline (183.821 us; speedup 1.0000x reference)
//
#include <hip/hip_runtime.h>

// GraphSAGE 2-layer. Gathers: bf16 tables, fp32 accum, 4 chains/wave.
// GEMMs: bf16 MFMA 16x16x32. mean(x)@W == mean(x@W): layer-2 gathers
// 64B rows of t2=bf16(h@Wn2).
// R21 (resubmit R22: prior bench hit GPUAcquisitionTimeout, no data):
// delete k_bucket_csr. Both gather kernels work on 32-node blocks
// (= quarter of a 128-node bucket), so each block counting-sorts its own
// bucket's unsorted slab (5KB) in LDS, then gathers with LDS edge-index
// reads (~40cy) instead of global (~300-900cy serial in every iter's
// chain). CSR (starts/degs/sorted pairs) never materialized. Sort VALU/
// LDS work hides under co-resident blocks' gather latency (R17's free-
// tail argument). 4x redundant sort per bucket = 16MB coalesced L3-hot
// reads, ~free. Occupancy unchanged (wave-capped 8 blk/CU; cap<=2048).
// Main gather: 2 nodes x 4 slots x 8 lanes x uint4 (1KB/instr, granule
// 4). b32add: 2 nodes x 4 slots x 8 lanes x uint2 (512B/instr).
// Pipeline: memset cursor; k_partition (+cvt feat->bf16, +weight
// transpose); k_gather_fused; k_gather_b32add.
// NOTE: harness re-poisons d_ws (268MB) each iter = fixed ~44us in dur_us.

#define SPAN        128
#define SPAN_SHIFT  7
#define PART_BLOCK  1024
#define PART_EPT    4
#define NBMAX       1024
#define LDS_S       72

typedef __attribute__((ext_vector_type(8))) short bf16x8;
typedef __attribute__((ext_vector_type(4))) float f32x4;

__device__ __forceinline__ unsigned bf16_rne(float f) {
    unsigned u = __float_as_uint(f);
    return (u + 0x7FFFu + ((u >> 16) & 1u)) >> 16;
}
__device__ __forceinline__ float bf_lo(unsigned u) { return __uint_as_float(u << 16); }
__device__ __forceinline__ float bf_hi(unsigned u) { return __uint_as_float(u & 0xFFFF0000u); }

// Partition + feat->bf16 cvt + weight transpose.
// wt layout: [mat][c][k] bf16, mat0=Ws1^T, mat1=Wn1^T, mat2=[Wn2|Ws2]^T.
__global__ __launch_bounds__(PART_BLOCK) void k_partition(
    const int* __restrict__ src, const int* __restrict__ dst,
    int* __restrict__ cursor, unsigned int* __restrict__ pairs,
    int E, int cap,
    const float* __restrict__ feat, unsigned short* __restrict__ xh, long total8,
    const float* __restrict__ ws1, const float* __restrict__ wn1,
    const float* __restrict__ ws2, const float* __restrict__ wn2,
    unsigned short* __restrict__ wt)
{
    const int tid = threadIdx.x;
    for (long i = (long)blockIdx.x * PART_BLOCK + tid; i < total8;
         i += (long)gridDim.x * PART_BLOCK) {
        const float4 a = ((const float4*)feat)[i * 2];
        const float4 b = ((const float4*)feat)[i * 2 + 1];
        uint4 o;
        o.x = bf16_rne(a.x) | (bf16_rne(a.y) << 16);
        o.y = bf16_rne(a.z) | (bf16_rne(a.w) << 16);
        o.z = bf16_rne(b.x) | (bf16_rne(b.y) << 16);
        o.w = bf16_rne(b.z) | (bf16_rne(b.w) << 16);
        ((uint4*)xh)[i] = o;
    }
    if (blockIdx.x < 12) {
        int j = blockIdx.x * PART_BLOCK + tid;   // < 12288
        int mat = j >> 12, rem = j & 4095;
        int c = rem >> 6, k = rem & 63;
        float v;
        if (mat == 0)      v = ws1[k * 64 + c];
        else if (mat == 1) v = wn1[k * 64 + c];
        else               v = (c < 32) ? wn2[k * 32 + c] : ws2[k * 32 + (c - 32)];
        wt[(mat << 12) + (c << 6) + k] = (unsigned short)bf16_rne(v);
    }

    __shared__ int cnt[NBMAX];
    __shared__ int gbase[NBMAX];
    __shared__ int lcur[NBMAX];
    cnt[tid] = 0; lcur[tid] = 0;
    __syncthreads();

    int sv[PART_EPT], bv[PART_EPT];
    const int e0 = blockIdx.x * (PART_BLOCK * PART_EPT) + tid;
    #pragma unroll
    for (int j = 0; j < PART_EPT; ++j) {
        int e = e0 + j * PART_BLOCK;
        bv[j] = -1;
        if (e < E) {
            int s = src[e], d = dst[e];
            bv[j] = d >> SPAN_SHIFT;
            sv[j] = s | ((d & (SPAN - 1)) << 24);
            atomicAdd(&cnt[bv[j]], 1);
        }
    }
    __syncthreads();
    if (cnt[tid] > 0) gbase[tid] = atomicAdd(&cursor[tid], cnt[tid]);
    __syncthreads();
    #pragma unroll
    for (int j = 0; j < PART_EPT; ++j) {
        if (bv[j] >= 0) {
            int r = gbase[bv[j]] + atomicAdd(&lcur[bv[j]], 1);
            if (r < cap) pairs[(size_t)bv[j] * cap + r] = (unsigned int)sv[j];
        }
    }
}

// Fused sort+gather+GEMM. 256 thr = 4 waves; block = 32 nodes (quarter
// bucket). Phase 0: counting-sort bucket's unsorted slab into LDS
// sorted[] (dlocal order) + pref/cnt = local CSR. Phase 1: gather means
// for wave's 8 nodes (2 nodes x 4 slots x 8 lanes x uint4 = 1KB/instr,
// indices from LDS). Phase 2: MFMA per wave = cols [16w,16w+16) of 32
// rows: L1 self(global xh)+neigh(sM), relu+b1 -> sH; L2 -> t2/out.
__global__ __launch_bounds__(256) void k_gather_fused(
    const unsigned short* __restrict__ xh,     // [N,64] bf16
    const unsigned int* __restrict__ pairs,    // unsorted bucket slabs
    const int* __restrict__ cursor,            // per-bucket edge counts
    const unsigned short* __restrict__ wt,     // [3][64][64] bf16 c-major
    const float* __restrict__ b1, const float* __restrict__ b2,
    unsigned short* __restrict__ t2,           // [N,32] bf16
    float* __restrict__ outp,                  // [N,32] f32
    int n, int cap)
{
    __shared__ __align__(16) unsigned short sM[32 * LDS_S];  // mean rows
    __shared__ __align__(16) unsigned short sH[32 * LDS_S];  // h rows
    __shared__ int cnt[SPAN];
    __shared__ int pref[SPAN];
    __shared__ int lcur[SPAN];
    extern __shared__ unsigned int sorted[];                 // [cap]
    const int tid  = threadIdx.x;
    const int w    = tid >> 6, lane = tid & 63;
    const int quad = lane >> 4, lm = lane & 15;   // MFMA lane split
    const int half = lane >> 5;                   // gather: node select
    const int q    = (lane >> 3) & 3;             // gather: slot (granule 4)
    const int c    = lane & 7;                    // gather: 16B chunk
    const int gm0  = blockIdx.x * 32;
    const int B    = gm0 >> SPAN_SHIFT;           // bucket id
    const int dbase = gm0 & (SPAN - 1);           // dlocal of block's node 0

    // ---- phase 0: counting sort of bucket B into LDS ----
    if (tid < SPAN) { cnt[tid] = 0; lcur[tid] = 0; }
    if (tid == 0) sorted[0] = 0;                  // masked-slot fallback
    __syncthreads();
    int m = cursor[B]; if (m > cap) m = cap;
    const size_t pb = (size_t)B * cap;
    for (int i = tid; i < m; i += 256)
        atomicAdd(&cnt[pairs[pb + i] >> 24], 1);
    __syncthreads();
    if (tid < SPAN) pref[tid] = cnt[tid];
    __syncthreads();
    for (int off = 1; off < SPAN; off <<= 1) {
        int v = 0;
        if (tid < SPAN && tid >= off) v = pref[tid - off];
        __syncthreads();
        if (tid < SPAN) pref[tid] += v;
        __syncthreads();
    }
    for (int i = tid; i < m; i += 256) {
        unsigned int p = pairs[pb + i];
        int r = p >> 24;
        int base = r ? pref[r - 1] : 0;
        sorted[base + atomicAdd(&lcur[r], 1)] = p & 0xFFFFFFu;
    }
    __syncthreads();

    // ---- phase 1: gather means for the wave's 8 nodes ----
    const int v0 = gm0 + w * 8;
    int e[4], end[4], dg[4];
    #pragma unroll
    for (int j = 0; j < 4; ++j) {
        int no = w * 8 + j * 2 + half;            // node offset in block
        int v  = gm0 + no;
        int dl = dbase + no;                      // dlocal in bucket
        if (v < n) {
            int bb = dl ? pref[dl - 1] : 0;
            dg[j] = cnt[dl]; e[j] = bb + q; end[j] = bb + dg[j];
        } else { dg[j] = 0; e[j] = 0; end[j] = 0; }
    }
    float ga[4][8];
    #pragma unroll
    for (int j = 0; j < 4; ++j)
        #pragma unroll
        for (int k = 0; k < 8; ++k) ga[j][k] = 0.f;

    while ((e[0] < end[0]) | (e[1] < end[1]) | (e[2] < end[2]) | (e[3] < end[3])) {
        uint4 u[4]; float mm[4];
        #pragma unroll
        for (int j = 0; j < 4; ++j) {
            bool p = e[j] < end[j];
            mm[j] = p ? 1.f : 0.f;
            int idx = p ? e[j] : 0;
            int s = (int)sorted[idx];             // LDS index read
            s = s < n ? s : n - 1;                // clamp vs garbage slots
            u[j] = *(const uint4*)&xh[(size_t)s * 64 + c * 8];
        }
        #pragma unroll
        for (int j = 0; j < 4; ++j) {
            ga[j][0] = fmaf(mm[j], bf_lo(u[j].x), ga[j][0]);
            ga[j][1] = fmaf(mm[j], bf_hi(u[j].x), ga[j][1]);
            ga[j][2] = fmaf(mm[j], bf_lo(u[j].y), ga[j][2]);
            ga[j][3] = fmaf(mm[j], bf_hi(u[j].y), ga[j][3]);
            ga[j][4] = fmaf(mm[j], bf_lo(u[j].z), ga[j][4]);
            ga[j][5] = fmaf(mm[j], bf_hi(u[j].z), ga[j][5]);
            ga[j][6] = fmaf(mm[j], bf_lo(u[j].w), ga[j][6]);
            ga[j][7] = fmaf(mm[j], bf_hi(u[j].w), ga[j][7]);
            e[j] += 4;
        }
    }
    #pragma unroll
    for (int j = 0; j < 4; ++j) {
        #pragma unroll
        for (int d = 8; d <= 16; d <<= 1) {   // reduce over slots, stay in half
            #pragma unroll
            for (int k = 0; k < 8; ++k) ga[j][k] += __shfl_xor(ga[j][k], d);
        }
        int v = v0 + j * 2 + half;
        if ((lane & 24) == 0 && v < n) {      // slot-0 lanes of each half
            float f = dg[j] ? 1.f / (float)dg[j] : 0.f;
            uint4 o;
            o.x = bf16_rne(ga[j][0] * f) | (bf16_rne(ga[j][1] * f) << 16);
            o.y = bf16_rne(ga[j][2] * f) | (bf16_rne(ga[j][3] * f) << 16);
            o.z = bf16_rne(ga[j][4] * f) | (bf16_rne(ga[j][5] * f) << 16);
            o.w = bf16_rne(ga[j][6] * f) | (bf16_rne(ga[j][7] * f) << 16);
            *(uint4*)&sM[(w * 8 + j * 2 + half) * LDS_S + c * 8] = o;
        }
    }
    __syncthreads();

    // ---- phase 2a: layer-1, wave w = h cols [16w,16w+16) of 32 rows ----
    f32x4 acc1[2];
    acc1[0] = (f32x4){0.f, 0.f, 0.f, 0.f};
    acc1[1] = (f32x4){0.f, 0.f, 0.f, 0.f};
    #pragma unroll
    for (int mt = 0; mt < 2; ++mt) {
        const int rowG = gm0 + mt * 16 + lm;
        const int rA = rowG < n ? rowG : n - 1;   // clamped -> garbage, stores guarded
        #pragma unroll
        for (int kt = 0; kt < 2; ++kt) {
            bf16x8 a  = *(const bf16x8*)&xh[(size_t)rA * 64 + kt * 32 + quad * 8];
            bf16x8 am = *(const bf16x8*)&sM[(mt * 16 + lm) * LDS_S + kt * 32 + quad * 8];
            bf16x8 bs = *(const bf16x8*)&wt[((w * 16 + lm) << 6) + kt * 32 + quad * 8];
            bf16x8 bn = *(const bf16x8*)&wt[(1 << 12) + ((w * 16 + lm) << 6) + kt * 32 + quad * 8];
            acc1[mt] = __builtin_amdgcn_mfma_f32_16x16x32_bf16(a,  bs, acc1[mt], 0, 0, 0);
            acc1[mt] = __builtin_amdgcn_mfma_f32_16x16x32_bf16(am, bn, acc1[mt], 0, 0, 0);
        }
    }
    {
        float bb = b1[w * 16 + lm];
        #pragma unroll
        for (int mt = 0; mt < 2; ++mt) {
            #pragma unroll
            for (int r = 0; r < 4; ++r) {
                float hv = fmaxf(acc1[mt][r] + bb, 0.f);
                sH[(mt * 16 + quad * 4 + r) * LDS_S + w * 16 + lm] =
                    (unsigned short)bf16_rne(hv);
            }
        }
    }
    __syncthreads();

    // ---- phase 2b: layer-2, [t2|out_self] cols = h @ [Wn2|Ws2] ----
    f32x4 acc2[2];
    acc2[0] = (f32x4){0.f, 0.f, 0.f, 0.f};
    acc2[1] = (f32x4){0.f, 0.f, 0.f, 0.f};
    #pragma unroll
    for (int mt = 0; mt < 2; ++mt) {
        #pragma unroll
        for (int kt = 0; kt < 2; ++kt) {
            bf16x8 a = *(const bf16x8*)&sH[(mt * 16 + lm) * LDS_S + kt * 32 + quad * 8];
            bf16x8 b = *(const bf16x8*)&wt[(2 << 12) + ((w * 16 + lm) << 6) + kt * 32 + quad * 8];
            acc2[mt] = __builtin_amdgcn_mfma_f32_16x16x32_bf16(a, b, acc2[mt], 0, 0, 0);
        }
    }
    #pragma unroll
    for (int mt = 0; mt < 2; ++mt) {
        if (w < 2) {
            #pragma unroll
            for (int r = 0; r < 4; ++r) {
                int gm = gm0 + mt * 16 + quad * 4 + r;
                if (gm < n)
                    t2[(size_t)gm * 32 + w * 16 + lm] = (unsigned short)bf16_rne(acc2[mt][r]);
            }
        } else {
            float bb = b2[(w - 2) * 16 + lm];
            #pragma unroll
            for (int r = 0; r < 4; ++r) {
                int gm = gm0 + mt * 16 + quad * 4 + r;
                if (gm < n)
                    outp[(size_t)gm * 32 + (w - 2) * 16 + lm] = acc2[mt][r] + bb;
            }
        }
    }
}

// Second gather with own in-block sort. Block = 32 nodes (quarter
// bucket); same counting sort into LDS; gather t2 rows: 2 nodes x 4
// slots x 8 lanes x uint2 = 512B/instr (granule 4). out += mean(t2).
__global__ __launch_bounds__(256) void k_gather_b32add(
    const unsigned short* __restrict__ t2,
    const unsigned int* __restrict__ pairs,
    const int* __restrict__ cursor,
    float* __restrict__ outp, int n, int cap)
{
    __shared__ int cnt[SPAN];
    __shared__ int pref[SPAN];
    __shared__ int lcur[SPAN];
    extern __shared__ unsigned int sorted[];
    const int tid  = threadIdx.x;
    const int w    = tid >> 6, lane = tid & 63;
    const int half = lane >> 5;                // node select within pair
    const int q    = (lane >> 3) & 3;          // slot (granule 4)
    const int c    = lane & 7;                 // 8B chunk (4 bf16)
    const int gm0  = blockIdx.x * 32;
    const int B    = gm0 >> SPAN_SHIFT;
    const int dbase = gm0 & (SPAN - 1);

    // ---- counting sort of bucket B into LDS ----
    if (tid < SPAN) { cnt[tid] = 0; lcur[tid] = 0; }
    if (tid == 0) sorted[0] = 0;
    __syncthreads();
    int m = cursor[B]; if (m > cap) m = cap;
    const size_t pb = (size_t)B * cap;
    for (int i = tid; i < m; i += 256)
        atomicAdd(&cnt[pairs[pb + i] >> 24], 1);
    __syncthreads();
    if (tid < SPAN) pref[tid] = cnt[tid];
    __syncthreads();
    for (int off = 1; off < SPAN; off <<= 1) {
        int v = 0;
        if (tid < SPAN && tid >= off) v = pref[tid - off];
        __syncthreads();
        if (tid < SPAN) pref[tid] += v;
        __syncthreads();
    }
    for (int i = tid; i < m; i += 256) {
        unsigned int p = pairs[pb + i];
        int r = p >> 24;
        int base = r ? pref[r - 1] : 0;
        sorted[base + atomicAdd(&lcur[r], 1)] = p & 0xFFFFFFu;
    }
    __syncthreads();

    // ---- gather ----
    const int v0 = gm0 + w * 8;
    int e[4], end[4], dg[4];
    #pragma unroll
    for (int j = 0; j < 4; ++j) {
        int no = w * 8 + j * 2 + half;
        int v  = gm0 + no;
        int dl = dbase + no;
        if (v < n) {
            int bb = dl ? pref[dl - 1] : 0;
            dg[j] = cnt[dl]; e[j] = bb + q; end[j] = bb + dg[j];
        } else { dg[j] = 0; e[j] = 0; end[j] = 0; }
    }
    float ga[4][4];
    #pragma unroll
    for (int j = 0; j < 4; ++j)
        #pragma unroll
        for (int k = 0; k < 4; ++k) ga[j][k] = 0.f;

    while ((e[0] < end[0]) | (e[1] < end[1]) | (e[2] < end[2]) | (e[3] < end[3])) {
        uint2 u[4]; float mm[4];
        #pragma unroll
        for (int j = 0; j < 4; ++j) {
            bool p = e[j] < end[j];
            mm[j] = p ? 1.f : 0.f;
            int idx = p ? e[j] : 0;
            int s = (int)sorted[idx];
            s = s < n ? s : n - 1;
            u[j] = *(const uint2*)&t2[(size_t)s * 32 + c * 4];
        }
        #pragma unroll
        for (int j = 0; j < 4; ++j) {
            ga[j][0] = fmaf(mm[j], bf_lo(u[j].x), ga[j][0]);
            ga[j][1] = fmaf(mm[j], bf_hi(u[j].x), ga[j][1]);
            ga[j][2] = fmaf(mm[j], bf_lo(u[j].y), ga[j][2]);
            ga[j][3] = fmaf(mm[j], bf_hi(u[j].y), ga[j][3]);
            e[j] += 4;
        }
    }
    #pragma unroll
    for (int j = 0; j < 4; ++j) {
        #pragma unroll
        for (int d = 8; d <= 16; d <<= 1) {   // reduce over slots, stay in half
            #pragma unroll
            for (int k = 0; k < 4; ++k) ga[j][k] += __shfl_xor(ga[j][k], d);
        }
        int v = v0 + j * 2 + half;
        if ((lane & 24) == 0 && v < n && dg[j] > 0) {   // slot-0 lanes of each half
            float f = 1.f / (float)dg[j];
            float4 o = *(const float4*)&outp[(size_t)v * 32 + c * 4];
            o.x += ga[j][0] * f; o.y += ga[j][1] * f;
            o.z += ga[j][2] * f; o.w += ga[j][3] * f;
            *(float4*)&outp[(size_t)v * 32 + c * 4] = o;
        }
    }
}

extern "C" void kernel_launch(void* const* d_in, const int* in_sizes, int n_in,
                              void* d_out, int out_size, void* d_ws, size_t ws_size,
                              hipStream_t stream) {
    const float* feat = (const float*)d_in[0];
    const int*   src  = (const int*)d_in[1];
    const int*   dst  = (const int*)d_in[2];
    const float* ws1  = (const float*)d_in[3];
    const float* wn1  = (const float*)d_in[4];
    const float* b1   = (const float*)d_in[5];
    const float* ws2  = (const float*)d_in[6];
    const float* wn2  = (const float*)d_in[7];
    const float* b2   = (const float*)d_in[8];
    float* out = (float*)d_out;

    const int N = in_sizes[0] / 64;
    const int E = in_sizes[1];
    const int nB = (N + SPAN - 1) >> SPAN_SHIFT;

    int cap = ((E + nB - 1) / nB);
    cap = ((cap + cap / 4) + 63) & ~63;
    {
        size_t fixedBytes = NBMAX * 4 + 3 * 4096 * 2
                          + (size_t)N * 64 * 2       // xh
                          + (size_t)N * 32 * 2       // t2
                          + 16384;
        size_t remain = (ws_size > fixedBytes) ? (ws_size - fixedBytes) : 0;
        size_t capMax = remain / ((size_t)nB * 4);
        if ((size_t)cap > capMax) cap = (int)(capMax & ~(size_t)3);
    }
    if (cap > 2048) cap = 2048;   // LDS sorted[] budget: 8KB dyn keeps 8 blk/CU

    char* base = (char*)d_ws;
    int* cursor = (int*)base;                                    // [1024]
    unsigned short* wt = (unsigned short*)(base + NBMAX * 4);    // [3][64][64] bf16
    unsigned int* pairs = (unsigned int*)(base + NBMAX * 4 + 24576);
    size_t mOff = ((size_t)NBMAX * 4 + 24576 + (size_t)nB * cap * 4 + 4096 + 255) & ~(size_t)255;
    unsigned short* xh = (unsigned short*)(base + mOff);         // [N,64] bf16
    unsigned short* t2 = xh + (size_t)N * 64;                    // [N,32] bf16

    hipMemsetAsync(cursor, 0, NBMAX * 4, stream);

    const long total8 = (long)N * 64 / 8;
    const int pblocks = (E + PART_BLOCK * PART_EPT - 1) / (PART_BLOCK * PART_EPT);
    k_partition<<<pblocks, PART_BLOCK, 0, stream>>>(
        src, dst, cursor, pairs, E, cap,
        feat, xh, total8, ws1, wn1, ws2, wn2, wt);

    const int fblocks = (N + 31) / 32;   // 32 nodes per block (8/wave)
    const size_t dynLds = (size_t)cap * 4;

    k_gather_fused<<<fblocks, 256, dynLds, stream>>>(
        xh, pairs, cursor, wt, b1, b2, t2, out, N, cap);
    k_gather_b32add<<<fblocks, 256, dynLds, stream>>>(
        t2, pairs, cursor, out, N, cap);
}

// Round 10
// 181.088 us; speedup vs baseline: 1.0151x; 1.0151x over previous
//
#include <hip/hip_runtime.h>

// GraphSAGE 2-layer. Gathers: bf16 tables, fp32 accum, 4 chains/wave.
// GEMMs: bf16 MFMA 16x16x32. mean(x)@W == mean(x@W): layer-2 gathers
// 64B rows of t2=bf16(h@Wn2).
// R23: REVERT to R20 (181.9us best). R21/R22's in-block sort fired its
// falsifier: fused 55->62us, FETCH +6.4MB (slab re-reads not L3-free),
// bank conflicts 400K->1.57M (sort atomics), and the LDS-index win was
// nil because the gather is THROUGHPUT-bound (R15/R16/R18: MLP,
// in-flight, index-latency all non-binding; only byte cuts move it).
// Both gathers now sit at their granule-4 byte floors; k_bucket_csr is
// cheaper than its deletion; fp8 table rejected (absmax at threshold).
// Pipeline: memset cursor; k_partition (+cvt feat->bf16, +weight
// transpose); k_bucket_csr (LDS counting sort); k_gather_fused;
// k_gather_b32add (out += mean of t2 rows).
// NOTE: harness re-poisons d_ws (268MB) each iter = fixed ~44us in dur_us.

#define SPAN        128
#define SPAN_SHIFT  7
#define PART_BLOCK  1024
#define PART_EPT    4
#define NBMAX       1024
#define LDS_S       72

typedef __attribute__((ext_vector_type(8))) short bf16x8;
typedef __attribute__((ext_vector_type(4))) float f32x4;

__device__ __forceinline__ unsigned bf16_rne(float f) {
    unsigned u = __float_as_uint(f);
    return (u + 0x7FFFu + ((u >> 16) & 1u)) >> 16;
}
__device__ __forceinline__ float bf_lo(unsigned u) { return __uint_as_float(u << 16); }
__device__ __forceinline__ float bf_hi(unsigned u) { return __uint_as_float(u & 0xFFFF0000u); }

// Partition + feat->bf16 cvt + weight transpose.
// wt layout: [mat][c][k] bf16, mat0=Ws1^T, mat1=Wn1^T, mat2=[Wn2|Ws2]^T.
__global__ __launch_bounds__(PART_BLOCK) void k_partition(
    const int* __restrict__ src, const int* __restrict__ dst,
    int* __restrict__ cursor, unsigned int* __restrict__ pairs,
    int E, int cap,
    const float* __restrict__ feat, unsigned short* __restrict__ xh, long total8,
    const float* __restrict__ ws1, const float* __restrict__ wn1,
    const float* __restrict__ ws2, const float* __restrict__ wn2,
    unsigned short* __restrict__ wt)
{
    const int tid = threadIdx.x;
    for (long i = (long)blockIdx.x * PART_BLOCK + tid; i < total8;
         i += (long)gridDim.x * PART_BLOCK) {
        const float4 a = ((const float4*)feat)[i * 2];
        const float4 b = ((const float4*)feat)[i * 2 + 1];
        uint4 o;
        o.x = bf16_rne(a.x) | (bf16_rne(a.y) << 16);
        o.y = bf16_rne(a.z) | (bf16_rne(a.w) << 16);
        o.z = bf16_rne(b.x) | (bf16_rne(b.y) << 16);
        o.w = bf16_rne(b.z) | (bf16_rne(b.w) << 16);
        ((uint4*)xh)[i] = o;
    }
    if (blockIdx.x < 12) {
        int j = blockIdx.x * PART_BLOCK + tid;   // < 12288
        int mat = j >> 12, rem = j & 4095;
        int c = rem >> 6, k = rem & 63;
        float v;
        if (mat == 0)      v = ws1[k * 64 + c];
        else if (mat == 1) v = wn1[k * 64 + c];
        else               v = (c < 32) ? wn2[k * 32 + c] : ws2[k * 32 + (c - 32)];
        wt[(mat << 12) + (c << 6) + k] = (unsigned short)bf16_rne(v);
    }

    __shared__ int cnt[NBMAX];
    __shared__ int gbase[NBMAX];
    __shared__ int lcur[NBMAX];
    cnt[tid] = 0; lcur[tid] = 0;
    __syncthreads();

    int sv[PART_EPT], bv[PART_EPT];
    const int e0 = blockIdx.x * (PART_BLOCK * PART_EPT) + tid;
    #pragma unroll
    for (int j = 0; j < PART_EPT; ++j) {
        int e = e0 + j * PART_BLOCK;
        bv[j] = -1;
        if (e < E) {
            int s = src[e], d = dst[e];
            bv[j] = d >> SPAN_SHIFT;
            sv[j] = s | ((d & (SPAN - 1)) << 24);
            atomicAdd(&cnt[bv[j]], 1);
        }
    }
    __syncthreads();
    if (cnt[tid] > 0) gbase[tid] = atomicAdd(&cursor[tid], cnt[tid]);
    __syncthreads();
    #pragma unroll
    for (int j = 0; j < PART_EPT; ++j) {
        if (bv[j] >= 0) {
            int r = gbase[bv[j]] + atomicAdd(&lcur[bv[j]], 1);
            if (r < cap) pairs[(size_t)bv[j] * cap + r] = (unsigned int)sv[j];
        }
    }
}

// Per bucket: LDS counting sort by dlocal, in-place coalesced writeback.
__global__ __launch_bounds__(256) void k_bucket_csr(
    unsigned int* __restrict__ pairs,
    const int* __restrict__ cursor,
    int* __restrict__ starts, int* __restrict__ degs,
    int N, int cap)
{
    __shared__ int cnt[SPAN];
    __shared__ int pref[SPAN];
    __shared__ int lcur[SPAN];
    extern __shared__ unsigned int sorted[];
    const int tid = threadIdx.x;
    const int b = blockIdx.x;
    if (tid < SPAN) { cnt[tid] = 0; lcur[tid] = 0; }
    __syncthreads();

    int m = cursor[b]; if (m > cap) m = cap;
    const size_t pb = (size_t)b * cap;

    for (int i = tid; i < m; i += 256)
        atomicAdd(&cnt[pairs[pb + i] >> 24], 1);
    __syncthreads();

    if (tid < SPAN) pref[tid] = cnt[tid];
    __syncthreads();
    for (int off = 1; off < SPAN; off <<= 1) {
        int v = 0;
        if (tid < SPAN && tid >= off) v = pref[tid - off];
        __syncthreads();
        if (tid < SPAN) pref[tid] += v;
        __syncthreads();
    }

    for (int i = tid; i < m; i += 256) {
        unsigned int p = pairs[pb + i];
        int r = p >> 24;
        int base = (r == 0) ? 0 : pref[r - 1];
        int pos = base + atomicAdd(&lcur[r], 1);
        sorted[pos] = p & 0xFFFFFFu;
    }
    __syncthreads();
    for (int i = tid; i < m; i += 256) pairs[pb + i] = sorted[i];
    if (tid < SPAN) {
        int node = (b << SPAN_SHIFT) + tid;
        if (node < N) {
            int base = (tid == 0) ? 0 : pref[tid - 1];
            starts[node] = (int)pb + base;
            degs[node]   = cnt[tid];
        }
    }
}

// Fused gather+GEMM. 256 thr = 4 waves; block = 32 nodes; wave owns 8
// nodes as 4 chains x 2 lane-halves. Per chain-load: 2 nodes x 4 slots x
// 8 lanes x uint4 = 1KB/instr, granule 4 rows/node. fp32 acc, shfl_xor
// 8/16 reduce (within half), mean -> sM (LDS). barrier. Wave w computes
// cols [16w,16w+16) of 32 rows: L1 self(global xh) + neigh(sM) MFMA,
// relu+b1 -> sH; barrier; L2 MFMA -> t2 (w<2) / out+b2 (w>=2). Weights
// from L2-hot global wt.
__global__ __launch_bounds__(256) void k_gather_fused(
    const unsigned short* __restrict__ xh,     // [N,64] bf16
    const unsigned int* __restrict__ esrc,
    const int* __restrict__ starts, const int* __restrict__ degs,
    const unsigned short* __restrict__ wt,     // [3][64][64] bf16 c-major
    const float* __restrict__ b1, const float* __restrict__ b2,
    unsigned short* __restrict__ t2,           // [N,32] bf16
    float* __restrict__ outp,                  // [N,32] f32
    int n)
{
    __shared__ __align__(16) unsigned short sM[32 * LDS_S];  // mean rows
    __shared__ __align__(16) unsigned short sH[32 * LDS_S];  // h rows
    const int w = threadIdx.x >> 6, lane = threadIdx.x & 63;
    const int quad = lane >> 4, lm = lane & 15;   // MFMA lane split
    const int half = lane >> 5;                   // gather: node select
    const int q    = (lane >> 3) & 3;             // gather: slot (granule 4)
    const int c    = lane & 7;                    // gather: 16B chunk
    const int gm0  = blockIdx.x * 32;
    const int v0   = gm0 + w * 8;

    // ---- gather: means for the wave's 8 nodes ----
    int e[4], end[4], dg[4];
    #pragma unroll
    for (int j = 0; j < 4; ++j) {
        int v = v0 + j * 2 + half;
        if (v < n) { int b = starts[v]; dg[j] = degs[v]; e[j] = b + q; end[j] = b + dg[j]; }
        else { dg[j] = 0; e[j] = 0; end[j] = 0; }
    }
    float ga[4][8];
    #pragma unroll
    for (int j = 0; j < 4; ++j)
        #pragma unroll
        for (int k = 0; k < 8; ++k) ga[j][k] = 0.f;

    while ((e[0] < end[0]) | (e[1] < end[1]) | (e[2] < end[2]) | (e[3] < end[3])) {
        uint4 u[4]; float m[4];
        #pragma unroll
        for (int j = 0; j < 4; ++j) {
            bool p = e[j] < end[j];
            m[j] = p ? 1.f : 0.f;
            int idx = p ? e[j] : 0;
            int s = (int)(esrc[idx] & 0xFFFFFFu);
            s = s < n ? s : n - 1;            // clamp vs garbage slab slots
            u[j] = *(const uint4*)&xh[(size_t)s * 64 + c * 8];
        }
        #pragma unroll
        for (int j = 0; j < 4; ++j) {
            ga[j][0] = fmaf(m[j], bf_lo(u[j].x), ga[j][0]);
            ga[j][1] = fmaf(m[j], bf_hi(u[j].x), ga[j][1]);
            ga[j][2] = fmaf(m[j], bf_lo(u[j].y), ga[j][2]);
            ga[j][3] = fmaf(m[j], bf_hi(u[j].y), ga[j][3]);
            ga[j][4] = fmaf(m[j], bf_lo(u[j].z), ga[j][4]);
            ga[j][5] = fmaf(m[j], bf_hi(u[j].z), ga[j][5]);
            ga[j][6] = fmaf(m[j], bf_lo(u[j].w), ga[j][6]);
            ga[j][7] = fmaf(m[j], bf_hi(u[j].w), ga[j][7]);
            e[j] += 4;
        }
    }
    #pragma unroll
    for (int j = 0; j < 4; ++j) {
        #pragma unroll
        for (int d = 8; d <= 16; d <<= 1) {   // reduce over slots, stay in half
            #pragma unroll
            for (int k = 0; k < 8; ++k) ga[j][k] += __shfl_xor(ga[j][k], d);
        }
        int v = v0 + j * 2 + half;
        if ((lane & 24) == 0 && v < n) {      // slot-0 lanes of each half
            float f = dg[j] ? 1.f / (float)dg[j] : 0.f;
            uint4 o;
            o.x = bf16_rne(ga[j][0] * f) | (bf16_rne(ga[j][1] * f) << 16);
            o.y = bf16_rne(ga[j][2] * f) | (bf16_rne(ga[j][3] * f) << 16);
            o.z = bf16_rne(ga[j][4] * f) | (bf16_rne(ga[j][5] * f) << 16);
            o.w = bf16_rne(ga[j][6] * f) | (bf16_rne(ga[j][7] * f) << 16);
            *(uint4*)&sM[(w * 8 + j * 2 + half) * LDS_S + c * 8] = o;
        }
    }
    __syncthreads();

    // ---- layer-1: wave w computes h cols [16w,16w+16) of the 32 rows ----
    f32x4 acc1[2];
    acc1[0] = (f32x4){0.f, 0.f, 0.f, 0.f};
    acc1[1] = (f32x4){0.f, 0.f, 0.f, 0.f};
    #pragma unroll
    for (int mt = 0; mt < 2; ++mt) {
        const int rowG = gm0 + mt * 16 + lm;
        const int rA = rowG < n ? rowG : n - 1;   // clamped -> garbage, stores guarded
        #pragma unroll
        for (int kt = 0; kt < 2; ++kt) {
            bf16x8 a  = *(const bf16x8*)&xh[(size_t)rA * 64 + kt * 32 + quad * 8];
            bf16x8 am = *(const bf16x8*)&sM[(mt * 16 + lm) * LDS_S + kt * 32 + quad * 8];
            bf16x8 bs = *(const bf16x8*)&wt[((w * 16 + lm) << 6) + kt * 32 + quad * 8];
            bf16x8 bn = *(const bf16x8*)&wt[(1 << 12) + ((w * 16 + lm) << 6) + kt * 32 + quad * 8];
            acc1[mt] = __builtin_amdgcn_mfma_f32_16x16x32_bf16(a,  bs, acc1[mt], 0, 0, 0);
            acc1[mt] = __builtin_amdgcn_mfma_f32_16x16x32_bf16(am, bn, acc1[mt], 0, 0, 0);
        }
    }
    // h = relu(acc1 + b1) -> sH cols [16w,16w+16)
    {
        float bb = b1[w * 16 + lm];
        #pragma unroll
        for (int mt = 0; mt < 2; ++mt) {
            #pragma unroll
            for (int r = 0; r < 4; ++r) {
                float hv = fmaxf(acc1[mt][r] + bb, 0.f);
                sH[(mt * 16 + quad * 4 + r) * LDS_S + w * 16 + lm] =
                    (unsigned short)bf16_rne(hv);
            }
        }
    }
    __syncthreads();

    // ---- layer-2: [t2|out_self] cols [16w,16w+16) = h @ [Wn2|Ws2] ----
    f32x4 acc2[2];
    acc2[0] = (f32x4){0.f, 0.f, 0.f, 0.f};
    acc2[1] = (f32x4){0.f, 0.f, 0.f, 0.f};
    #pragma unroll
    for (int mt = 0; mt < 2; ++mt) {
        #pragma unroll
        for (int kt = 0; kt < 2; ++kt) {
            bf16x8 a = *(const bf16x8*)&sH[(mt * 16 + lm) * LDS_S + kt * 32 + quad * 8];
            bf16x8 b = *(const bf16x8*)&wt[(2 << 12) + ((w * 16 + lm) << 6) + kt * 32 + quad * 8];
            acc2[mt] = __builtin_amdgcn_mfma_f32_16x16x32_bf16(a, b, acc2[mt], 0, 0, 0);
        }
    }
    #pragma unroll
    for (int mt = 0; mt < 2; ++mt) {
        if (w < 2) {
            #pragma unroll
            for (int r = 0; r < 4; ++r) {
                int gm = gm0 + mt * 16 + quad * 4 + r;
                if (gm < n)
                    t2[(size_t)gm * 32 + w * 16 + lm] = (unsigned short)bf16_rne(acc2[mt][r]);
            }
        } else {
            float bb = b2[(w - 2) * 16 + lm];
            #pragma unroll
            for (int r = 0; r < 4; ++r) {
                int gm = gm0 + mt * 16 + quad * 4 + r;
                if (gm < n)
                    outp[(size_t)gm * 32 + (w - 2) * 16 + lm] = acc2[mt][r] + bb;
            }
        }
    }
}

// Second gather, granule 4: 2 nodes x 4 slots x 8 lanes x uint2
// = 512B/instr; wave owns 8 nodes (4 chains x 2 lane-halves); block = 32
// nodes. Traffic E[ceil(d/4)]*4*64B ~= 0.72 KB/node (-32% vs granule 8).
// out += mean(t2 rows).
__global__ __launch_bounds__(256) void k_gather_b32add(
    const unsigned short* __restrict__ t2,
    const unsigned int* __restrict__ esrc,
    const int* __restrict__ starts, const int* __restrict__ degs,
    float* __restrict__ outp, int n)
{
    const int w = threadIdx.x >> 6, lane = threadIdx.x & 63;
    const int half = lane >> 5;                // node select within pair
    const int q    = (lane >> 3) & 3;          // slot (granule 4)
    const int c    = lane & 7;                 // 8B chunk (4 bf16)
    const int v0 = (blockIdx.x * 4 + w) * 8;
    if (v0 >= n) return;

    int e[4], end[4], dg[4];
    #pragma unroll
    for (int j = 0; j < 4; ++j) {
        int v = v0 + j * 2 + half;
        if (v < n) { int b = starts[v]; dg[j] = degs[v]; e[j] = b + q; end[j] = b + dg[j]; }
        else { dg[j] = 0; e[j] = 0; end[j] = 0; }
    }
    float ga[4][4];
    #pragma unroll
    for (int j = 0; j < 4; ++j)
        #pragma unroll
        for (int k = 0; k < 4; ++k) ga[j][k] = 0.f;

    while ((e[0] < end[0]) | (e[1] < end[1]) | (e[2] < end[2]) | (e[3] < end[3])) {
        uint2 u[4]; float m[4];
        #pragma unroll
        for (int j = 0; j < 4; ++j) {
            bool p = e[j] < end[j];
            m[j] = p ? 1.f : 0.f;
            int idx = p ? e[j] : 0;
            int s = (int)(esrc[idx] & 0xFFFFFFu);
            s = s < n ? s : n - 1;
            u[j] = *(const uint2*)&t2[(size_t)s * 32 + c * 4];
        }
        #pragma unroll
        for (int j = 0; j < 4; ++j) {
            ga[j][0] = fmaf(m[j], bf_lo(u[j].x), ga[j][0]);
            ga[j][1] = fmaf(m[j], bf_hi(u[j].x), ga[j][1]);
            ga[j][2] = fmaf(m[j], bf_lo(u[j].y), ga[j][2]);
            ga[j][3] = fmaf(m[j], bf_hi(u[j].y), ga[j][3]);
            e[j] += 4;
        }
    }
    #pragma unroll
    for (int j = 0; j < 4; ++j) {
        #pragma unroll
        for (int d = 8; d <= 16; d <<= 1) {   // reduce over slots, stay in half
            #pragma unroll
            for (int k = 0; k < 4; ++k) ga[j][k] += __shfl_xor(ga[j][k], d);
        }
        int v = v0 + j * 2 + half;
        if ((lane & 24) == 0 && v < n && dg[j] > 0) {   // slot-0 lanes of each half
            float f = 1.f / (float)dg[j];
            float4 o = *(const float4*)&outp[(size_t)v * 32 + c * 4];
            o.x += ga[j][0] * f; o.y += ga[j][1] * f;
            o.z += ga[j][2] * f; o.w += ga[j][3] * f;
            *(float4*)&outp[(size_t)v * 32 + c * 4] = o;
        }
    }
}

extern "C" void kernel_launch(void* const* d_in, const int* in_sizes, int n_in,
                              void* d_out, int out_size, void* d_ws, size_t ws_size,
                              hipStream_t stream) {
    const float* feat = (const float*)d_in[0];
    const int*   src  = (const int*)d_in[1];
    const int*   dst  = (const int*)d_in[2];
    const float* ws1  = (const float*)d_in[3];
    const float* wn1  = (const float*)d_in[4];
    const float* b1   = (const float*)d_in[5];
    const float* ws2  = (const float*)d_in[6];
    const float* wn2  = (const float*)d_in[7];
    const float* b2   = (const float*)d_in[8];
    float* out = (float*)d_out;

    const int N = in_sizes[0] / 64;
    const int E = in_sizes[1];
    const int nB = (N + SPAN - 1) >> SPAN_SHIFT;

    int cap = ((E + nB - 1) / nB);
    cap = ((cap + cap / 4) + 63) & ~63;
    {
        size_t fixedBytes = NBMAX * 4 + 3 * 4096 * 2 + (size_t)N * 8
                          + (size_t)N * 64 * 2       // xh
                          + (size_t)N * 32 * 2       // t2
                          + 16384;
        size_t remain = (ws_size > fixedBytes) ? (ws_size - fixedBytes) : 0;
        size_t capMax = remain / ((size_t)nB * 4);
        if ((size_t)cap > capMax) cap = (int)(capMax & ~(size_t)3);
    }

    char* base = (char*)d_ws;
    int* cursor = (int*)base;                                    // [1024]
    unsigned short* wt = (unsigned short*)(base + NBMAX * 4);    // [3][64][64] bf16
    unsigned int* pairs = (unsigned int*)(base + NBMAX * 4 + 24576);
    size_t sOff = ((size_t)NBMAX * 4 + 24576 + (size_t)nB * cap * 4 + 4096 + 255) & ~(size_t)255;
    int* starts = (int*)(base + sOff);                           // [N]
    int* degs   = starts + N;                                    // [N]
    size_t mOff = (sOff + (size_t)N * 8 + 255) & ~(size_t)255;
    unsigned short* xh = (unsigned short*)(base + mOff);         // [N,64] bf16
    unsigned short* t2 = xh + (size_t)N * 64;                    // [N,32] bf16

    hipMemsetAsync(cursor, 0, NBMAX * 4, stream);

    const long total8 = (long)N * 64 / 8;
    const int pblocks = (E + PART_BLOCK * PART_EPT - 1) / (PART_BLOCK * PART_EPT);
    k_partition<<<pblocks, PART_BLOCK, 0, stream>>>(
        src, dst, cursor, pairs, E, cap,
        feat, xh, total8, ws1, wn1, ws2, wn2, wt);
    k_bucket_csr<<<nB, 256, (size_t)cap * 4, stream>>>(pairs, cursor, starts, degs, N, cap);

    const int fblocks = (N + 31) / 32;   // 32 nodes per block (8/wave)

    k_gather_fused<<<fblocks, 256, 0, stream>>>(
        xh, pairs, starts, degs, wt, b1, b2, t2, out, N);
    k_gather_b32add<<<fblocks, 256, 0, stream>>>(t2, pairs, starts, degs, out, N);
}